// Round 1
// 144.504 us; speedup vs baseline: 1.1084x; 1.1084x over previous
//
#include <hip/hip_runtime.h>
#include <hip/hip_bf16.h>
#include <stdint.h>
#include <stddef.h>

typedef unsigned short u16;
typedef unsigned int   u32;
typedef __attribute__((ext_vector_type(8))) short bf16x8;  // 8 bf16 = 4 VGPRs
typedef __attribute__((ext_vector_type(4))) float f32x4;   // MFMA C/D

#define LOG2E   1.44269504f
#define EXP_OFF 23.0831206f   // 16 * log2(e)

static __device__ __forceinline__ float bf2f(u16 v) {
    u32 u = ((u32)v) << 16; float f; __builtin_memcpy(&f, &u, 4); return f;
}
static __device__ __forceinline__ u16 f2bf(float f) {
    u32 u; __builtin_memcpy(&u, &f, 4);
    u32 r = (u + 0x7fffu + ((u >> 16) & 1u)) >> 16; return (u16)r;
}
static __device__ __forceinline__ float as_f(u32 u) { float f; __builtin_memcpy(&f, &u, 4); return f; }
static __device__ __forceinline__ u32   as_u(float f) { u32 u; __builtin_memcpy(&u, &f, 4); return u; }

// fp32-vs-bf16 input detection (wave 0)
static __device__ __forceinline__ int detect_f32_wave0(const void* x, int t) {
    const u32* xw = (const u32*)x;
    int bad = 0;
    #pragma unroll
    for (int k = 0; k < 4; ++k) {
        u32 wv = xw[(t << 2) + k];
        int e = (wv >> 7) & 0xff;
        bad += (e >= 160);
    }
    unsigned long long m = __ballot(bad > 0);
    return (__popcll(m) >= 8) ? 1 : 0;
}

// V workspace layout (pre-fragmented for MFMA B-operand, per batch):
//   elem_addr = cblk*65536 + jblk*512 + (quad4*16 + clo)*8 + jlo
//   where c = cblk*16 + clo, j = jblk*32 + quad4*8 + jlo.
// A wave B-frag load (lane = quad*16+n16 reads 16B) is 1KB fully contiguous.

// ---------------------------------------------------------------------------
// Kernel 1 (MFMA proj, replaces scalar-VALU proj):
//   Grid = (it*5 + g)*4 + n : 64 i-tiles x 5 och-groups(64) x 4 batches.
//   bid&3 = batch keeps the batch<->XCD L2 affinity flash relies on.
//   256 threads / 4 waves; wave w owns i-frag i0 + w*16.
//   W-slice (64 och x 256 c) staged ONCE to LDS as bf16, XOR-swizzled
//   (col ^ ((row&7)<<3)) -> B-frag ds_read_b128 is bank-conflict-free.
//   A-frags (x) direct from global (16 lanes x 4B = 64B coalesced lines),
//   prefetched one k-chunk ahead. NO barriers inside the k-loop.
//   Outputs:
//     qws [n][i][32] bf16, pre-scaled by log2(e)
//     kws [n][i][32] bf16
//     vws pre-fragmented (layout above)
// ---------------------------------------------------------------------------
__global__ __launch_bounds__(256) void qkv_proj_mfma(
    const void* __restrict__ x,
    const void* __restrict__ Wq, const void* __restrict__ bq,
    const void* __restrict__ Wk, const void* __restrict__ bk,
    const void* __restrict__ Wv, const void* __restrict__ bv,
    u16* __restrict__ qws, u16* __restrict__ kws, u16* __restrict__ vws,
    int n_off, int nshiftp)
{
    __shared__ u16 Wl[64 * 256];   // 32 KB, swizzled bf16 W-slice
    __shared__ int dtf;

    const int t    = threadIdx.x;
    const int bid  = blockIdx.x;
    const int n_w  = bid & ((1 << nshiftp) - 1);
    const int rest = bid >> nshiftp;
    const int g    = rest % 5;        // 0 = q+k, 1..4 = v quarters
    const int it   = rest / 5;        // i-tile (64 i)
    const int n_g  = n_off + n_w;
    const int i0   = it << 6;

    if (t < 64) { int f = detect_f32_wave0(x, t); if (t == 0) dtf = f; }
    __syncthreads();
    const bool isf32 = (dtf != 0);

    // ---- stage W slice (64 rows x 256 cols) into LDS, swizzled bf16 ----
    #pragma unroll
    for (int k = 0; k < 16; ++k) {
        int idx  = t + (k << 8);
        int row  = idx >> 6;            // 0..63 (wave-uniform per k)
        int col4 = (idx & 63) << 2;     // 0..252 step 4
        const void* src; int srow;
        if (g == 0) {
            if (row < 32) { src = Wq; srow = row; }
            else          { src = Wk; srow = row - 32; }
        } else { src = Wv; srow = ((g - 1) << 6) + row; }
        ushort4 h;
        if (isf32) {
            float4 wv = *((const float4*)((const float*)src + srow * 256 + col4));
            h.x = f2bf(wv.x); h.y = f2bf(wv.y); h.z = f2bf(wv.z); h.w = f2bf(wv.w);
        } else {
            h = *((const ushort4*)((const u16*)src + srow * 256 + col4));
        }
        *(ushort4*)&Wl[(row << 8) + (col4 ^ ((row & 7) << 3))] = h;
    }
    __syncthreads();

    const int lane = t & 63;
    const int w    = t >> 6;          // wave -> i-frag
    const int n16  = lane & 15;
    const int quad = lane >> 4;
    const int i_b  = i0 + (w << 4);
    const int i    = i_b + n16;
    const int swz  = (n16 & 7) << 3;

    f32x4 acc[4];
    #pragma unroll
    for (int f = 0; f < 4; ++f) acc[f] = (f32x4){0.f, 0.f, 0.f, 0.f};

    // ---- k-loop: 8 chunks of 32 c; A direct-global, B from LDS ----
    if (isf32) {
        const float* xp = (const float*)x
            + (((size_t)(n_g * 256 + (quad << 3))) << 12) + i;
        float af[8];
        #pragma unroll
        for (int e = 0; e < 8; ++e) af[e] = xp[(size_t)e << 12];
        #pragma unroll
        for (int c8 = 0; c8 < 8; ++c8) {
            bf16x8 a;
            #pragma unroll
            for (int e = 0; e < 8; ++e) a[e] = (short)f2bf(af[e]);
            if (c8 < 7) {
                const float* xn = xp + (((size_t)(c8 + 1) << 5) << 12);
                #pragma unroll
                for (int e = 0; e < 8; ++e) af[e] = xn[(size_t)e << 12];
            }
            const int c0 = c8 << 5;
            #pragma unroll
            for (int f = 0; f < 4; ++f) {
                const int brow = (f << 4) + n16;
                bf16x8 b = *(const bf16x8*)
                    &Wl[(brow << 8) + ((c0 + (quad << 3)) ^ swz)];
                acc[f] = __builtin_amdgcn_mfma_f32_16x16x32_bf16(a, b, acc[f], 0, 0, 0);
            }
        }
    } else {
        const u16* xp = (const u16*)x
            + (((size_t)(n_g * 256 + (quad << 3))) << 12) + i;
        u16 af[8];
        #pragma unroll
        for (int e = 0; e < 8; ++e) af[e] = xp[(size_t)e << 12];
        #pragma unroll
        for (int c8 = 0; c8 < 8; ++c8) {
            bf16x8 a;
            #pragma unroll
            for (int e = 0; e < 8; ++e) a[e] = (short)af[e];
            if (c8 < 7) {
                const u16* xn = xp + (((size_t)(c8 + 1) << 5) << 12);
                #pragma unroll
                for (int e = 0; e < 8; ++e) af[e] = xn[(size_t)e << 12];
            }
            const int c0 = c8 << 5;
            #pragma unroll
            for (int f = 0; f < 4; ++f) {
                const int brow = (f << 4) + n16;
                bf16x8 b = *(const bf16x8*)
                    &Wl[(brow << 8) + ((c0 + (quad << 3)) ^ swz)];
                acc[f] = __builtin_amdgcn_mfma_f32_16x16x32_bf16(a, b, acc[f], 0, 0, 0);
            }
        }
    }

    // ---- epilogue: D frag is (col = n16 = och-local, row = quad*4+r = i) ----
    if (g == 0) {
        #pragma unroll
        for (int f = 0; f < 4; ++f) {
            const int ol   = (f << 4) + n16;     // 0..63
            const bool isq = (ol < 32);
            const int och  = isq ? ol : (ol - 32);
            float bias;
            if (isf32) bias = ((const float*)(isq ? bq : bk))[och];
            else       bias = bf2f(((const u16*)(isq ? bq : bk))[och]);
            u16* dst = (isq ? qws : kws) + (((size_t)n_w) << 17) + och;
            const float scale = isq ? LOG2E : 1.0f;
            #pragma unroll
            for (int r = 0; r < 4; ++r) {
                const int ii = i_b + (quad << 2) + r;
                dst[(size_t)ii << 5] = f2bf((acc[f][r] + bias) * scale);
            }
        }
    } else {
        #pragma unroll
        for (int f = 0; f < 4; ++f) {
            const int c = ((g - 1) << 6) + (f << 4) + n16;   // c&15 == n16
            float bias = isf32 ? ((const float*)bv)[c]
                               : bf2f(((const u16*)bv)[c]);
            const int i4 = i_b + (quad << 2);
            ushort4 h;
            h.x = f2bf(acc[f][0] + bias);
            h.y = f2bf(acc[f][1] + bias);
            h.z = f2bf(acc[f][2] + bias);
            h.w = f2bf(acc[f][3] + bias);
            const size_t addr = ((size_t)n_w << 20)
                + ((size_t)(c >> 4) << 16)          // cblk*65536
                + ((size_t)(i4 >> 5) << 9)          // jblk*512
                + (size_t)((((((i4 & 31) >> 3) << 4) + (c & 15)) << 3) + (i4 & 7));
            *(ushort4*)(vws + addr) = h;
        }
    }
}

// ---------------------------------------------------------------------------
// Kernel 2 (v9, unchanged): single-barrier PV-lag flash; V fragments direct
// from global in PRE-FRAGMENTED layout (1KB coalesced wave loads, L2-served
// via batch<->XCD affinity). LDS = double-buffered Ps only (+Dbuf alias).
// S: wave (qsub_s 0..3, jsub 0..3). PV: wave (cq 0..7 -> 32c, jq 0..1 -> 32j).
// NO min-occupancy launch bound (r6 spill lesson).
// ---------------------------------------------------------------------------
__global__ __launch_bounds__(1024) void flash_mfma6(
    const u16* __restrict__ qws, const u16* __restrict__ kws,
    const u16* __restrict__ vws, void* __restrict__ out,
    const void* __restrict__ x, int n_off, int nshift)
{
    __shared__ __align__(16) char arena[17920];
    __shared__ __align__(16) float lS[64];
    __shared__ int dtf;
    u16*   PsA  = (u16*)arena;                 // + par*4096 (elems)
    float* Dbuf = (float*)arena;               // epilogue alias

    const int t    = threadIdx.x;
    const int lane = t & 63;
    const int w    = t >> 6;          // 0..15
    const int n16  = lane & 15;
    const int quad = lane >> 4;
    const int bid  = blockIdx.x;
    const int n_w  = bid & ((1 << nshift) - 1);
    const int qt   = bid >> nshift;
    const int n_g  = n_off + n_w;
    const int i0   = qt << 6;

    if (t < 64) {
        int f = detect_f32_wave0(x, t);
        if (t == 0) dtf = f;
        lS[t] = 0.f;
    }

    const u16* qb = qws + (((size_t)n_w) << 17);
    const u16* kb = kws + (((size_t)n_w) << 17);
    const u16* vb = vws + (((size_t)n_w) << 20);

    // S decomposition
    const int qsub_s = w & 3;
    const int jsub   = w >> 2;
    // PV decomposition: 32 c x 32 j per wave
    const int cq = w & 7;
    const int jq = w >> 3;

    const bf16x8 qfrag =
        *(const bf16x8*)(qb + ((size_t)(i0 + (qsub_s << 4) + n16) << 5) + (quad << 3));

    f32x4 acc[4][2];
    #pragma unroll
    for (int a = 0; a < 4; ++a)
        #pragma unroll
        for (int b = 0; b < 2; ++b) acc[a][b] = (f32x4){0.f, 0.f, 0.f, 0.f};
    float lp[4] = {0.f, 0.f, 0.f, 0.f};

    const int jcol = (jsub << 4) + n16;
    const int j8   = jcol >> 3;
    const int jlo  = jcol & 7;
    const int ksw  = (jq << 2) + quad;

    // Pre-fragmented V base: cblk = cq*2 (+1 for second frag), jblk = tile*2+jq
    // addr = cblk*65536 + jblk*512 + lane*8; per-tile step = 1024 elems.
    const u16* vfp0 = vb + ((size_t)(cq << 1) << 16) + ((size_t)jq << 9)
                         + ((size_t)((quad << 4) + n16) << 3);
    const u16* vfp1 = vfp0 + 65536;

    bf16x8 kreg, vf0, vf1;

    // ---- prologue: S(0) into parity 0; prefetch K(1), V-frags for PV(0) ----
    kreg = *(const bf16x8*)(kb + ((size_t)((jsub << 4) + n16) << 5) + (quad << 3));
    {
        u16* Ps = PsA;
        const f32x4 z = {0.f, 0.f, 0.f, 0.f};
        f32x4 s = __builtin_amdgcn_mfma_f32_16x16x32_bf16(qfrag, kreg, z, 0, 0, 0);
        #pragma unroll
        for (int r = 0; r < 4; ++r) {
            const int qrow = (qsub_s << 4) + (quad << 2) + r;
            float p = exp2f(s[r] - EXP_OFF);
            u32 u = as_u(p) & 0xffff0000u;
            lp[r] += as_f(u);
            Ps[qrow * 64 + ((j8 ^ (qrow & 7)) << 3) + jlo] = (u16)(u >> 16);
        }
        kreg = *(const bf16x8*)(kb + ((size_t)(64 + (jsub << 4) + n16) << 5) + (quad << 3));
        vf0 = *(const bf16x8*)(vfp0);
        vf1 = *(const bf16x8*)(vfp1);
    }
    __syncthreads();

    // ---- main loop: ONE barrier per tile ----
    for (int tile = 1; tile < 64; ++tile) {
        const int par  = tile & 1;
        u16* Psc = PsA + (par << 12);
        u16* Psp = PsA + ((par ^ 1) << 12);

        // PV(tile-1): pa from LDS, vf from prefetched coalesced global regs
        bf16x8 pa[4];
        #pragma unroll
        for (int qs = 0; qs < 4; ++qs) {
            const int qrow = (qs << 4) + n16;
            pa[qs] = *(const bf16x8*)&Psp[qrow * 64 + ((ksw ^ (qrow & 7)) << 3)];
        }
        #pragma unroll
        for (int qs = 0; qs < 4; ++qs) {
            acc[qs][0] = __builtin_amdgcn_mfma_f32_16x16x32_bf16(pa[qs], vf0, acc[qs][0], 0, 0, 0);
            acc[qs][1] = __builtin_amdgcn_mfma_f32_16x16x32_bf16(pa[qs], vf1, acc[qs][1], 0, 0, 0);
        }

        // prefetch V-frags for PV(tile) (used next iteration)
        vf0 = *(const bf16x8*)(vfp0 + ((size_t)tile << 10));
        vf1 = *(const bf16x8*)(vfp1 + ((size_t)tile << 10));

        // S(tile) + softmax + P write
        const f32x4 z = {0.f, 0.f, 0.f, 0.f};
        f32x4 s = __builtin_amdgcn_mfma_f32_16x16x32_bf16(qfrag, kreg, z, 0, 0, 0);
        #pragma unroll
        for (int r = 0; r < 4; ++r) {
            const int qrow = (qsub_s << 4) + (quad << 2) + r;
            float p = exp2f(s[r] - EXP_OFF);
            u32 u = as_u(p) & 0xffff0000u;
            lp[r] += as_f(u);
            Psc[qrow * 64 + ((j8 ^ (qrow & 7)) << 3) + jlo] = (u16)(u >> 16);
        }

        // prefetch K for tile+1
        if (tile < 63) {
            const int j0n = (tile + 1) << 6;
            kreg = *(const bf16x8*)(kb + ((size_t)(j0n + (jsub << 4) + n16) << 5)
                                    + (quad << 3));
        }
        __syncthreads();
    }

    // ---- final PV(63): parity 1, vf holds jblk of tile 63 ----
    {
        u16* Psp = PsA + (1 << 12);
        bf16x8 pa[4];
        #pragma unroll
        for (int qs = 0; qs < 4; ++qs) {
            const int qrow = (qs << 4) + n16;
            pa[qs] = *(const bf16x8*)&Psp[qrow * 64 + ((ksw ^ (qrow & 7)) << 3)];
        }
        #pragma unroll
        for (int qs = 0; qs < 4; ++qs) {
            acc[qs][0] = __builtin_amdgcn_mfma_f32_16x16x32_bf16(pa[qs], vf0, acc[qs][0], 0, 0, 0);
            acc[qs][1] = __builtin_amdgcn_mfma_f32_16x16x32_bf16(pa[qs], vf1, acc[qs][1], 0, 0, 0);
        }
    }

    // ---- l reduction ----
    #pragma unroll
    for (int r = 0; r < 4; ++r) {
        lp[r] += __shfl_xor(lp[r], 1);
        lp[r] += __shfl_xor(lp[r], 2);
        lp[r] += __shfl_xor(lp[r], 4);
        lp[r] += __shfl_xor(lp[r], 8);
    }
    if (n16 == 0) {
        #pragma unroll
        for (int r = 0; r < 4; ++r)
            atomicAdd(&lS[(qsub_s << 4) + (quad << 2) + r], lp[r]);
    }
    __syncthreads();
    if (t < 64) lS[t] = 1.0f / lS[t];
    const bool isf32 = (dtf != 0);

    // ---- epilogue: 4 chunks of 64 c; combine jq-partials in Dbuf, store ----
    for (int chunk = 0; chunk < 4; ++chunk) {
        __syncthreads();   // Dbuf free; rl ready; Ps reads complete (chunk 0)
        if (jq == 1 && (cq >> 1) == chunk) {
            #pragma unroll
            for (int qs = 0; qs < 4; ++qs)
                #pragma unroll
                for (int cs = 0; cs < 2; ++cs)
                    *(f32x4*)&Dbuf[(((cq & 1) << 5) + (cs << 4) + n16) * 68 +
                                   (qs << 4) + (quad << 2)] = acc[qs][cs];
        }
        __syncthreads();
        if (jq == 0 && (cq >> 1) == chunk) {
            #pragma unroll
            for (int qs = 0; qs < 4; ++qs)
                #pragma unroll
                for (int cs = 0; cs < 2; ++cs) {
                    float* p = &Dbuf[(((cq & 1) << 5) + (cs << 4) + n16) * 68 +
                                     (qs << 4) + (quad << 2)];
                    f32x4 d = *(f32x4*)p;
                    d += acc[qs][cs];
                    *(f32x4*)p = d;
                }
        }
        __syncthreads();
        // store: 1024 threads x 4 q
        const int c_l = t >> 4;
        const int qg  = (t & 15) << 2;
        float4 d  = *(float4*)&Dbuf[c_l * 68 + qg];
        float4 rl = *(float4*)&lS[qg];
        const int c_glob = (chunk << 6) + c_l;
        const size_t ob = (((size_t)(n_g * 256 + c_glob)) << 12) + i0 + qg;
        if (isf32) {
            float4 o = make_float4(d.x * rl.x, d.y * rl.y, d.z * rl.z, d.w * rl.w);
            *(float4*)((float*)out + ob) = o;
        } else {
            union { uint2 v; u16 h[4]; } o;
            o.h[0] = f2bf(d.x * rl.x);
            o.h[1] = f2bf(d.y * rl.y);
            o.h[2] = f2bf(d.z * rl.z);
            o.h[3] = f2bf(d.w * rl.w);
            *(uint2*)((u16*)out + ob) = o.v;
        }
    }
}

extern "C" void kernel_launch(void* const* d_in, const int* in_sizes, int n_in,
                              void* d_out, int out_size, void* d_ws, size_t ws_size,
                              hipStream_t stream)
{
    const void* x  = d_in[0];
    const void* Wq = d_in[1];
    const void* bq = d_in[2];
    const void* Wk = d_in[3];
    const void* bk = d_in[4];
    const void* Wv = d_in[5];
    const void* bv = d_in[6];

    const size_t full_need = (size_t)(4u * 4096u) * (32 + 32 + 256) * 2; // 10 MB
    if (ws_size >= full_need) {
        u16* qws = (u16*)d_ws;
        u16* kws = qws + (size_t)4 * 4096 * 32;
        u16* vws = kws + (size_t)4 * 4096 * 32;
        // grid = (it*5 + g)*4 + n  -> bid&3 = batch (XCD affinity, as flash)
        qkv_proj_mfma<<<dim3(1280), dim3(256), 0, stream>>>(
            x, Wq, bq, Wk, bk, Wv, bv, qws, kws, vws, 0, 2);
        flash_mfma6<<<dim3(256), dim3(1024), 0, stream>>>(
            qws, kws, vws, d_out, x, 0, 2);
    } else {
        u16* qws = (u16*)d_ws;
        u16* kws = qws + (size_t)4096 * 32;
        u16* vws = kws + (size_t)4096 * 32;
        for (int n = 0; n < 4; ++n) {
            qkv_proj_mfma<<<dim3(320), dim3(256), 0, stream>>>(
                x, Wq, bq, Wk, bk, Wv, bv, qws, kws, vws, n, 0);
            flash_mfma6<<<dim3(64), dim3(1024), 0, stream>>>(
                qws, kws, vws, d_out, x, n, 0);
        }
    }
}